// Round 5
// baseline (378.978 us; speedup 1.0000x reference)
//
#include <hip/hip_runtime.h>

// Attend: out = softmax(causal(Q K^T * 0.125 + bias)) @ V
// B=4,H=16,N=1024,D=64. fp32 I/O, bf16 MFMA compute.
// Round 5: REGISTER DIET. launch_bounds caps VGPR at 128; r4's live state
// (~135-140: double bias buffer + sfr[4] + prefetch regs) spilled to
// scratch, putting ~16 dependent scratch reloads on every tile's exp
// path (~8k cyc/tile — the dominant stall). Changes vs r4:
//   (a) single bias reg buffer, prefetched 1 tile ahead (-16 VGPR)
//   (b) exp folded into the per-nt_ QK loop: sfr[4] -> one acc (-12 VGPR)
// Est. ~110 VGPR -> no spill. Structure otherwise identical (8 waves x
// 16 rows, dbuf K/V LDS, 1 barrier/tile, balanced strips, masked skip).

#define BHn 64
#define Nn 1024
#define Dn 64
#define NEG_BIG (-1e30f)
#define STR 72   // LDS row stride in shorts (144 B)

typedef __attribute__((ext_vector_type(8))) short short8;
typedef __attribute__((ext_vector_type(4))) float floatx4;
typedef __attribute__((ext_vector_type(4))) unsigned uint4v;

// Barrier without vmcnt(0) drain: own-LDS drain only; global prefetches
// stay in flight (counted vmcnt inserted by compiler at first use).
#define BARRIER_LDS()                                            \
    do {                                                         \
        asm volatile("s_waitcnt lgkmcnt(0)" ::: "memory");       \
        __builtin_amdgcn_s_barrier();                            \
    } while (0)

__device__ __forceinline__ unsigned cvt_pk_bf16(float lo, float hi) {
    unsigned r;
    asm("v_cvt_pk_bf16_f32 %0, %1, %2" : "=v"(r) : "v"(lo), "v"(hi));
    return r;   // packed {bf16(lo), bf16(hi)}, RNE
}

// ---- prefetch tile JT's K/V slice into regs (global, coalesced) ----
#define PREFETCH_KV(JT)                                                      \
    do {                                                                     \
        const float* kbn = kk + ((long)(bh * Nn + (JT) * 64)) * Dn + tid * 8;\
        kpf[0] = *(const floatx4*)(kbn);                                     \
        kpf[1] = *(const floatx4*)(kbn + 4);                                 \
        const float* vbn = v + ((long)(bh * Nn + (JT) * 64 + wave * 8)) * Dn \
                             + lane;                                         \
        _Pragma("unroll")                                                    \
        for (int r = 0; r < 8; ++r) vpf[r] = vbn[r * Dn];                    \
    } while (0)

// ---- stage regs -> LDS buffer BUF (cvt + one b128 write each) ----
#define STAGE_KV(BUF)                                                        \
    do {                                                                     \
        uint4v kw;                                                           \
        kw.x = cvt_pk_bf16(kpf[0][0], kpf[0][1]);                            \
        kw.y = cvt_pk_bf16(kpf[0][2], kpf[0][3]);                            \
        kw.z = cvt_pk_bf16(kpf[1][0], kpf[1][1]);                            \
        kw.w = cvt_pk_bf16(kpf[1][2], kpf[1][3]);                            \
        *(uint4v*)&k_s[BUF][krow][kcol] = kw;                                \
        uint4v vw;                                                           \
        vw.x = cvt_pk_bf16(vpf[0], vpf[1]);                                  \
        vw.y = cvt_pk_bf16(vpf[2], vpf[3]);                                  \
        vw.z = cvt_pk_bf16(vpf[4], vpf[5]);                                  \
        vw.w = cvt_pk_bf16(vpf[6], vpf[7]);                                  \
        *(uint4v*)&vt_s[BUF][lane][wave * 8] = vw;                           \
    } while (0)

// ---- bias loads for tile JT (skipped for wave-masked / OOB tiles) ----
#define LOAD_BIAS(JT)                                                        \
    do {                                                                     \
        if ((JT) <= diag_jt) {                                               \
            const float* bp = bias + bias_base                               \
                              + (long)(irow0 + lg * 4) * Nn + (JT) * 64 + ln;\
            _Pragma("unroll")                                                \
            for (int r = 0; r < 4; ++r)                                      \
                _Pragma("unroll")                                            \
                for (int c = 0; c < 4; ++c)                                  \
                    bv[c][r] = bp[r * Nn + c * 16];                          \
        }                                                                    \
    } while (0)

// ---- full compute of tile JT from buffer BUF; exp folded per-nt_ so only
//      one 4-reg acc is live; bias for JT+1 issued once bv is consumed ----
#define COMPUTE(BUF, JT)                                                     \
    do {                                                                     \
        if ((JT) <= diag_jt) {                                               \
            const bool diag = ((JT) == diag_jt);                             \
            _Pragma("unroll")                                                \
            for (int nt_ = 0; nt_ < 4; ++nt_) {                              \
                short8 b0 = *(const short8*)&k_s[BUF][nt_ * 16 + ln][lg * 8];\
                short8 b1 = *(const short8*)&k_s[BUF][nt_ * 16 + ln][32 + lg * 8];\
                floatx4 acc = {0.f, 0.f, 0.f, 0.f};                          \
                acc = __builtin_amdgcn_mfma_f32_16x16x32_bf16(qa[0], b0, acc, 0, 0, 0);\
                acc = __builtin_amdgcn_mfma_f32_16x16x32_bf16(qa[1], b1, acc, 0, 0, 0);\
                _Pragma("unroll")                                            \
                for (int r = 0; r < 4; ++r) {                                \
                    float sv = acc[r] * 0.125f + bv[nt_][r];                 \
                    if (diag) {                                              \
                        const int i_ = irow0 + lg * 4 + r;                   \
                        const int j_ = (JT) * 64 + nt_ * 16 + ln;            \
                        sv = (j_ > i_) ? NEG_BIG : sv;                       \
                    }                                                        \
                    const float p  = __expf(sv);                             \
                    const float po = __shfl_xor(p, 1);                       \
                    if (!(lane & 1))                                         \
                        *(unsigned*)&p_s[wave][lg * 4 + r][nt_ * 16 + ln] =  \
                            cvt_pk_bf16(p, po);                              \
                }                                                            \
            }                                                                \
            LOAD_BIAS((JT) + 1);   /* bv dead; prefetch next tile's bias */  \
            const short8 pa0 = *(const short8*)&p_s[wave][ln][lg * 8];       \
            const short8 pa1 = *(const short8*)&p_s[wave][ln][32 + lg * 8];  \
            __builtin_amdgcn_s_setprio(1);                                   \
            l_acc = __builtin_amdgcn_mfma_f32_16x16x32_bf16(pa0, ones, l_acc, 0, 0, 0);\
            l_acc = __builtin_amdgcn_mfma_f32_16x16x32_bf16(pa1, ones, l_acc, 0, 0, 0);\
            _Pragma("unroll")                                                \
            for (int dt = 0; dt < 4; ++dt) {                                 \
                short8 vb0 = *(const short8*)&vt_s[BUF][dt * 16 + ln][lg * 8];\
                short8 vb1 = *(const short8*)&vt_s[BUF][dt * 16 + ln][32 + lg * 8];\
                o_acc[dt] = __builtin_amdgcn_mfma_f32_16x16x32_bf16(pa0, vb0, o_acc[dt], 0, 0, 0);\
                o_acc[dt] = __builtin_amdgcn_mfma_f32_16x16x32_bf16(pa1, vb1, o_acc[dt], 0, 0, 0);\
            }                                                                \
            __builtin_amdgcn_s_setprio(0);                                   \
        } else { LOAD_BIAS((JT) + 1); }                                      \
    } while (0)

__global__ __launch_bounds__(512, 4) void attend_mfma(
    const float* __restrict__ q, const float* __restrict__ kk,
    const float* __restrict__ v, const float* __restrict__ bias,
    float* __restrict__ out)
{
    // ---- balanced (head, q-strip) decode: pair {c,c+256} -> (qs, 7-qs) ----
    const int b  = blockIdx.x;
    const int bh = b & 63;                   // 8 blocks/head, head -> XCD
    const int t  = b >> 6;                   // 0..7
    const int x  = (t + bh) & 3;
    const int qs = (t < 4) ? x : (7 - x);    // q-strip (128 rows), bijective
    const int nt = 2 * qs + 2;               // j-tiles for this block (even)

    const int tid  = threadIdx.x;
    const int lane = tid & 63;
    const int wave = tid >> 6;               // 0..7
    const int ln = lane & 15;                // MFMA n / m index
    const int lg = lane >> 4;                // MFMA k-group / row-group
    const int irow0   = qs * 128 + wave * 16;
    const int diag_jt = irow0 >> 6;          // wave's last active j-tile
    const long bias_base = ((long)bh) << 20; // bh * N * N
    const int krow = tid >> 3, kcol = (tid & 7) * 8;

    __shared__ short k_s[2][64][STR];        // K tiles, row-major [j][d]
    __shared__ short vt_s[2][64][STR];       // V tiles, transposed [d][j]
    __shared__ short p_s[8][16][STR];        // per-wave P tile [m][j]

    // ---- preload Q A-frags (rows irow0..irow0+15), fp32 -> bf16 ----
    short8 qa[2];
    {
        const float* qp = q + ((long)(bh * Nn + irow0 + ln)) * Dn + lg * 8;
#pragma unroll
        for (int kp = 0; kp < 2; ++kp) {
            floatx4 f0 = *(const floatx4*)(qp + kp * 32);
            floatx4 f1 = *(const floatx4*)(qp + kp * 32 + 4);
            union { short8 s; unsigned u[4]; } qq;
            qq.u[0] = cvt_pk_bf16(f0[0], f0[1]);
            qq.u[1] = cvt_pk_bf16(f0[2], f0[3]);
            qq.u[2] = cvt_pk_bf16(f1[0], f1[1]);
            qq.u[3] = cvt_pk_bf16(f1[2], f1[3]);
            qa[kp] = qq.s;
        }
    }

    short8 ones;
#pragma unroll
    for (int i = 0; i < 8; ++i) ones[i] = (short)0x3F80;   // bf16 1.0

    floatx4 o_acc[4];
#pragma unroll
    for (int dt = 0; dt < 4; ++dt) o_acc[dt] = (floatx4){0.f, 0.f, 0.f, 0.f};
    floatx4 l_acc = {0.f, 0.f, 0.f, 0.f};

    // ---- register prefetch buffers (kept deliberately small: no spill) ----
    floatx4 kpf[2];      // 8 floats: K slice (this thread)
    float   vpf[8];      // 8 floats: V slice (col=lane, 8 rows)
    float   bv[4][4];    // bias for the CURRENT tile (single buffer)

    // ---- prologue: tile 0 staged, tile 1 prefetched, bias 0 loaded ----
    PREFETCH_KV(0);
    LOAD_BIAS(0);
    STAGE_KV(0);
    if (nt > 1) PREFETCH_KV(1);
    BARRIER_LDS();

    // ---- main loop: unrolled by 2 (nt is always even) ----
    for (int jt = 0; jt < nt; jt += 2) {
        // even tile jt (buf 0): stage jt+1, prefetch jt+2
        STAGE_KV(1);                                  // tile jt+1 -> buf1
        if (jt + 2 < nt) PREFETCH_KV(jt + 2);
        COMPUTE(0, jt);                               // loads bias jt+1 inside
        BARRIER_LDS();

        // odd tile jt+1 (buf 1): stage jt+2, prefetch jt+3
        if (jt + 2 < nt) STAGE_KV(0);                 // tile jt+2 -> buf0
        if (jt + 3 < nt) PREFETCH_KV(jt + 3);
        COMPUTE(1, jt + 1);                           // loads bias jt+2 inside
        BARRIER_LDS();
    }

    // ---- epilogue: out = O / l, fp32 stores ----
#pragma unroll
    for (int r = 0; r < 4; ++r) {
        const float linv = 1.0f / l_acc[r];
        const long orow = ((long)(bh * Nn + irow0 + lg * 4 + r)) * Dn;
#pragma unroll
        for (int dt = 0; dt < 4; ++dt)
            out[orow + dt * 16 + ln] = o_acc[dt][r] * linv;
    }
}

extern "C" void kernel_launch(void* const* d_in, const int* in_sizes, int n_in,
                              void* d_out, int out_size, void* d_ws, size_t ws_size,
                              hipStream_t stream) {
    const float* q    = (const float*)d_in[0];
    const float* k    = (const float*)d_in[1];
    const float* v    = (const float*)d_in[2];
    const float* bias = (const float*)d_in[3];
    float* out = (float*)d_out;

    dim3 grid(512);    // 64 heads x 8 q-strips of 128 rows
    dim3 block(512);   // 8 waves x 16 rows
    attend_mfma<<<grid, block, 0, stream>>>(q, k, v, bias, out);
}